// Round 5
// baseline (284.039 us; speedup 1.0000x reference)
//
#include <hip/hip_runtime.h>
#include <hip/hip_bf16.h>

#define NN 4096
#define KK 64
#define AA 8
#define DD 128

#define XH_STRIDE 264   // shorts: 256 + 8 pad (rows 16B-aligned)
#define A_STRIDE  136
#define H2_STRIDE 136
#define XREG_SZ   16896 // 64 * 264 shorts = 33792 B

typedef __bf16 bf16x8 __attribute__((ext_vector_type(8)));
typedef __bf16 bf16x2 __attribute__((ext_vector_type(2)));
typedef float  f32x4  __attribute__((ext_vector_type(4)));

__device__ __forceinline__ short f2bf(float f) {
    unsigned u = __builtin_bit_cast(unsigned, f);
    u += 0x7FFFu + ((u >> 16) & 1u);   // RNE
    return (short)(u >> 16);
}
__device__ __forceinline__ float bf2f(short s) {
    unsigned u = ((unsigned)(unsigned short)s) << 16;
    return __builtin_bit_cast(float, u);
}
__device__ __forceinline__ unsigned f2bf2(float a, float b) {
#if __has_builtin(__builtin_amdgcn_cvt_pk_bf16_f32)
    bf16x2 r = __builtin_amdgcn_cvt_pk_bf16_f32(a, b);
    return __builtin_bit_cast(unsigned, r);
#else
    return ((unsigned)(unsigned short)f2bf(a)) | (((unsigned)(unsigned short)f2bf(b)) << 16);
#endif
}
__device__ __forceinline__ void store_bf8(short* dst, float4 a, float4 b) {
    uint4 v;
    v.x = f2bf2(a.x, a.y); v.y = f2bf2(a.z, a.w);
    v.z = f2bf2(b.x, b.y); v.w = f2bf2(b.z, b.w);
    *(uint4*)dst = v;
}

// R14: prep_all absorbs conv_bf16 (one launch fewer).
// blocks [0,96): weight pack (8 elems/thread, coalesced 16B stores)
// blocks [96,608): s1 precompute (8 nodes/block)
// blocks [608,7173): bf16 table conversion (u2e/r2e/ua2e)
__global__ void prep_all(const float* __restrict__ W1, const float* __restrict__ W2,
                         const float* __restrict__ A1, const float* __restrict__ A2,
                         const int* __restrict__ nodes, const float* __restrict__ u2e,
                         const float* __restrict__ r2e, const float* __restrict__ ua2e,
                         const float* __restrict__ ab1,
                         short* __restrict__ W1p, short* __restrict__ W2p,
                         short* __restrict__ A1p, short* __restrict__ A2p,
                         float* __restrict__ s1g,
                         short* __restrict__ u2b, short* __restrict__ r2b,
                         short* __restrict__ uab)
{
    if (blockIdx.x < 96) {
        const int t    = blockIdx.x * 256 + threadIdx.x;   // [0, 24576)
        const int idx8 = t * 8;
        const float* src; short* dst; int Ncols, ksl, idx;
        if (idx8 < 131072)      { src = W1; dst = W1p; Ncols = 256; ksl = 4; idx = idx8; }
        else if (idx8 < 163840) { src = W2; dst = W2p; Ncols = 128; ksl = 3; idx = idx8 - 131072; }
        else if (idx8 < 180224) { src = A1; dst = A1p; Ncols = 128; ksl = 2; idx = idx8 - 163840; }
        else                    { src = A2; dst = A2p; Ncols = 128; ksl = 2; idx = idx8 - 180224; }
        const int lane  = (idx >> 3) & 63;
        const int fi    = idx >> 9;
        const int kstep = fi & ((1 << ksl) - 1);
        const int ntile = fi >> ksl;
        const int k0 = kstep * 32 + (lane >> 4) * 8;
        const int nn = ntile * 16 + (lane & 15);
        short v[8];
#pragma unroll
        for (int j = 0; j < 8; ++j)
            v[j] = f2bf(src[(size_t)(k0 + j) * Ncols + nn]);
        *(uint4*)&dst[idx] = *(const uint4*)v;
    } else if (blockIdx.x < 608) {
        // s1[n] = ab1 + u2e[nodes[n]] @ A1[128:256,:], 8 nodes/block
        __shared__ float rows[8][DD];
        const int b = blockIdx.x - 96;
        {
            const int r  = threadIdx.x >> 5;
            const int c4 = (threadIdx.x & 31) * 4;
            const int node = nodes[b * 8 + r];
            *(float4*)&rows[r][c4] = *(const float4*)&u2e[(size_t)node * DD + c4];
        }
        __syncthreads();
        const int h = threadIdx.x >> 7;
        const int c = threadIdx.x & 127;
        const float ab = ab1[c];
        float acc[4] = {ab, ab, ab, ab};
#pragma unroll 4
        for (int i = 0; i < DD; ++i) {
            const float av = A1[(size_t)(DD + i) * DD + c];
#pragma unroll
            for (int j = 0; j < 4; ++j)
                acc[j] = fmaf(rows[h * 4 + j][i], av, acc[j]);
        }
#pragma unroll
        for (int j = 0; j < 4; ++j)
            s1g[(size_t)(b * 8 + h * 4 + j) * DD + c] = acc[j];
    } else {
        // stream-convert embedding tables to bf16 (RNE, same bits as old in-kernel cvt)
        const int t  = (blockIdx.x - 608) * 256 + threadIdx.x;
        const int e8 = t * 8;
        const float* src; short* dst; int off;
        if (e8 < 12800000)      { src = u2e;  dst = u2b; off = e8; }
        else if (e8 < 12804096) { src = r2e;  dst = r2b; off = e8 - 12800000; }
        else if (e8 < 13444096) { src = ua2e; dst = uab; off = e8 - 12804096; }
        else return;
        float4 a = *(const float4*)&src[off];
        float4 b = *(const float4*)&src[off + 4];
        store_bf8(&dst[off], a, b);
    }
}

// Register discipline (hard-won, R6/R8/R9):
//  - launch_bounds MUST stay (512,4): (512,6) caps regs ~85/wave -> acc spill (R6).
//    3 blocks/CU is closed (needs 6 waves/EU budget).
//  - R10: do not trade L2 bytes for LDS cycles (2Mx4N remap was -3.5%).
//  - R12: bf16 tables -> gathers 36->18/thread, FETCH 102->44MB, 200->164us.
//  - R13 POST-MORTEM: XOR bank-swizzle of b16 sites cut conflicts only 6% and
//    spilled (+7.4MB scratch writes). SQ_LDS_BANK_CONFLICT here is dominated by
//    inherent wave64 b128 read serialization (1KB/instr vs 128B/cy port), which
//    is TLP-hidden. Conflict-chasing is a DEAD END for this kernel.
//  - R14 (this round): merged staging. attrs DMA remapped per-wave-self-serve,
//    xA + xB both staged before one barrier -> all ~26 gather loads + DMA
//    pipeline in one window; R8/R9 fences deleted (gathers complete before any
//    MFMA, so no register-window overlap risk); GEMM1 runs ks0-15 unbroken.
template<bool BFT>
__launch_bounds__(512, 4)
__global__ void l2agg_mfma(
    const int* __restrict__ paths_rel,
    const int* __restrict__ paths_nbr,
    const int* __restrict__ attrs,
    const float* __restrict__ u2e,
    const float* __restrict__ r2e,
    const float* __restrict__ ua2e,
    const short* __restrict__ u2b,
    const short* __restrict__ r2b,
    const short* __restrict__ uab,
    const float* __restrict__ b1,
    const float* __restrict__ b2,
    const float* __restrict__ ab2,
    const float* __restrict__ A3,
    const float* __restrict__ ab3,
    const short* __restrict__ W1p,
    const short* __restrict__ W2p,
    const short* __restrict__ A1p,
    const short* __restrict__ A2p,
    const float* __restrict__ s1g,
    float* __restrict__ out)
{
    // xa: xA (stride 264) -> h1 (stride 264) -> a1 (stride 136)
    // xb: xB (stride 264) -> h2 (stride 136, persists to final reduce)
    __shared__ short xa[XREG_SZ];            // 33792 B
    __shared__ short xb[XREG_SZ];            // 33792 B
    __shared__ int   idx_u[512];             // attrs idx (dead after stage) -> partials
    __shared__ float wts8[512];              // per-wave softmax weights (wave-local)
    float* partials = (float*)idx_u;         // 512 floats, born after b5

    const int n    = blockIdx.x;
    const int tid  = threadIdx.x;
    const int lane = tid & 63;
    const int wv   = tid >> 6;    // 0..7
    const int mr   = lane & 15;
    const int q    = lane >> 4;

    // ---------- async DMA: attrs indices, per-wave self-serve layout ----------
    // Wave wv serves its own 8 paths P(pl) = wv*4 + (pl&3) + (pl>>2)*32, pl=0..7.
    // lane l: pl = l>>3, a = l&7 -> idx_u[wv*64 + l] = attrs[n*512 + P(pl)*8 + a].
    // No cross-wave dependency => only an intra-wave vmcnt drain is needed.
    {
        const int pl = lane >> 3;
        const int a  = lane & 7;
        const int p  = wv * 4 + (pl & 3) + (pl >> 2) * 32;
        const int* ab = attrs + (size_t)n * KK * AA;
        __builtin_amdgcn_global_load_lds(
            (const __attribute__((address_space(1))) void*)(ab + p * 8 + a),
            (__attribute__((address_space(3))) void*)(idx_u + wv * 64 + lane), 4, 0, 0);
    }

    // ---------- stage xA = [r1 | r2] for 64 paths ----------
#pragma unroll
    for (int pass = 0; pass < 2; ++pass) {
        const int p  = pass * 32 + (tid >> 4);
        const int t  = tid & 15;
        const int o  = t * 8;
        const int pk = n * KK + p;
        const int2 pr = *(const int2*)&paths_rel[pk * 2];
        const int i0 = pr.x;
        const int i1 = pr.y;
        if constexpr (BFT) {
            uint4 v1 = *(const uint4*)&r2b[(size_t)i0 * DD + o];
            uint4 v2 = *(const uint4*)&r2b[(size_t)i1 * DD + o];
            *(uint4*)&xa[p * XH_STRIDE + o]       = v1;
            *(uint4*)&xa[p * XH_STRIDE + 128 + o] = v2;
        } else {
            float4 r1a = *(const float4*)&r2e[(size_t)i0 * DD + o];
            float4 r1b = *(const float4*)&r2e[(size_t)i0 * DD + o + 4];
            float4 r2a = *(const float4*)&r2e[(size_t)i1 * DD + o];
            float4 r2b_ = *(const float4*)&r2e[(size_t)i1 * DD + o + 4];
            store_bf8(&xa[p * XH_STRIDE + o], r1a, r1b);
            store_bf8(&xa[p * XH_STRIDE + 128 + o], r2a, r2b_);
        }
    }

    // drain the DMA (and xA loads) so idx_u is readable by this wave
    asm volatile("s_waitcnt vmcnt(0)" ::: "memory");

    // ---------- stage xB = [ne | ae] -> xb (both passes, pre-barrier) ----------
#pragma unroll
    for (int s = 0; s < 2; ++s) {
        const int g  = lane >> 4;                 // quad 0..3
        const int p  = s * 32 + (tid >> 4);       // == wv*4 + g + s*32
        const int t  = tid & 15;
        const int og = t * 8;
        const int nb = paths_nbr[(size_t)n * KK + p];   // L1-broadcast across 16 lanes
        const int ib = wv * 64 + (s * 4 + g) * 8;       // this wave's idx slice
        if constexpr (BFT) {
            uint4 nev = *(const uint4*)&u2b[(size_t)nb * DD + og];
            float aes[8] = {0.f, 0.f, 0.f, 0.f, 0.f, 0.f, 0.f, 0.f};
#pragma unroll
            for (int a = 0; a < AA; ++a) {
                const int ai = idx_u[ib + a];
                uint4 w = *(const uint4*)&uab[(size_t)ai * DD + og];
                aes[0] += __builtin_bit_cast(float, w.x << 16);
                aes[1] += __builtin_bit_cast(float, w.x & 0xFFFF0000u);
                aes[2] += __builtin_bit_cast(float, w.y << 16);
                aes[3] += __builtin_bit_cast(float, w.y & 0xFFFF0000u);
                aes[4] += __builtin_bit_cast(float, w.z << 16);
                aes[5] += __builtin_bit_cast(float, w.z & 0xFFFF0000u);
                aes[6] += __builtin_bit_cast(float, w.w << 16);
                aes[7] += __builtin_bit_cast(float, w.w & 0xFFFF0000u);
            }
            *(uint4*)&xb[p * XH_STRIDE + og] = nev;
            uint4 pv;
            pv.x = f2bf2(aes[0], aes[1]); pv.y = f2bf2(aes[2], aes[3]);
            pv.z = f2bf2(aes[4], aes[5]); pv.w = f2bf2(aes[6], aes[7]);
            *(uint4*)&xb[p * XH_STRIDE + 128 + og] = pv;
        } else {
            float4 nea = *(const float4*)&u2e[(size_t)nb * DD + og];
            float4 neb = *(const float4*)&u2e[(size_t)nb * DD + og + 4];
            float4 aea = make_float4(0.f, 0.f, 0.f, 0.f);
            float4 aeb = make_float4(0.f, 0.f, 0.f, 0.f);
#pragma unroll
            for (int a = 0; a < AA; ++a) {
                const int ai = idx_u[ib + a];
                float4 va = *(const float4*)&ua2e[(size_t)ai * DD + og];
                float4 vb = *(const float4*)&ua2e[(size_t)ai * DD + og + 4];
                aea.x += va.x; aea.y += va.y; aea.z += va.z; aea.w += va.w;
                aeb.x += vb.x; aeb.y += vb.y; aeb.z += vb.z; aeb.w += vb.w;
            }
            store_bf8(&xb[p * XH_STRIDE + og], nea, neb);
            store_bf8(&xb[p * XH_STRIDE + 128 + og], aea, aeb);
        }
    }
    __syncthreads();   // B1: xa + xb ready (idx_u now dead)

    // ---------- GEMM1: ks 0..15 uninterrupted, 2-deep B prefetch ----------
    const short* W1b = W1p + wv * 2 * 16 * 512 + lane * 8;  // frag(nt,ks) = W1b[nt*8192 + ks*512]
    f32x4 acc1[4][2] = {};
    bf16x8 bfc[2], bfn[2];
#pragma unroll
    for (int nt = 0; nt < 2; ++nt) bfc[nt] = *(const bf16x8*)&W1b[nt * 8192];
#pragma unroll
    for (int ks = 0; ks < 16; ++ks) {
        if (ks < 15) {
#pragma unroll
            for (int nt = 0; nt < 2; ++nt)
                bfn[nt] = *(const bf16x8*)&W1b[nt * 8192 + (ks + 1) * 512];
        }
        const short* xs = (ks < 8) ? xa : xb;   // static under full unroll
        bf16x8 af[4];
#pragma unroll
        for (int mt = 0; mt < 4; ++mt)
            af[mt] = *(const bf16x8*)&xs[(mt * 16 + mr) * XH_STRIDE + (ks & 7) * 32 + q * 8];
#pragma unroll
        for (int nt = 0; nt < 2; ++nt)
#pragma unroll
            for (int mt = 0; mt < 4; ++mt)
                acc1[mt][nt] = __builtin_amdgcn_mfma_f32_16x16x32_bf16(af[mt], bfc[nt], acc1[mt][nt], 0, 0, 0);
        if (ks < 15) {
#pragma unroll
            for (int nt = 0; nt < 2; ++nt) bfc[nt] = bfn[nt];
        }
    }
    __syncthreads();   // B2: all GEMM1 reads done -> xa/xb writable

    // preload GEMM2 ks=0 B-frag; wave -> cols wv*16..wv*16+15 (mt4 x nt1: min regs)
    const short* W2b = W2p + wv * 8 * 512 + lane * 8;       // frag(ks) = W2b[ks*512]
    bf16x8 g2c = *(const bf16x8*)&W2b[0], g2n;

    // ---------- h1 = relu(acc1 + b1) -> xa ----------
#pragma unroll
    for (int nt = 0; nt < 2; ++nt) {
        const int col = (wv * 2 + nt) * 16 + mr;
        const float bb = b1[col];
#pragma unroll
        for (int mt = 0; mt < 4; ++mt)
#pragma unroll
            for (int r = 0; r < 4; r += 2) {
                unsigned pk2 = f2bf2(fmaxf(acc1[mt][nt][r] + bb, 0.f),
                                     fmaxf(acc1[mt][nt][r + 1] + bb, 0.f));
                xa[(mt * 16 + q * 4 + r)     * XH_STRIDE + col] = (short)pk2;
                xa[(mt * 16 + q * 4 + r + 1) * XH_STRIDE + col] = (short)(pk2 >> 16);
            }
    }
    __syncthreads();   // b3: h1 ready

    // ---------- GEMM2: h2 = relu(h1 @ W2 + b2), 2-deep B prefetch ----------
    f32x4 acc2[4] = {};
#pragma unroll
    for (int ks = 0; ks < 8; ++ks) {
        if (ks < 7) g2n = *(const bf16x8*)&W2b[(ks + 1) * 512];
        bf16x8 af[4];
#pragma unroll
        for (int mt = 0; mt < 4; ++mt)
            af[mt] = *(const bf16x8*)&xa[(mt * 16 + mr) * XH_STRIDE + ks * 32 + q * 8];
#pragma unroll
        for (int mt = 0; mt < 4; ++mt)
            acc2[mt] = __builtin_amdgcn_mfma_f32_16x16x32_bf16(af[mt], g2c, acc2[mt], 0, 0, 0);
        if (ks < 7) g2c = g2n;
    }

    // preload ALL GEMM3 B-frags + s1 (hidden under GEMM2 epilogue + b4)
    const short* A1b = A1p + wv * 4 * 512 + lane * 8;
    bf16x8 g3f[4];
#pragma unroll
    for (int ks = 0; ks < 4; ++ks) g3f[ks] = *(const bf16x8*)&A1b[ks * 512];
    const float s1v = s1g[(size_t)n * DD + wv * 16 + mr];

    // GEMM2 epilogue -> h2 into xb (stride 136; xb dead since B2)
    {
        const int col = wv * 16 + mr;
        const float bb = b2[col];
#pragma unroll
        for (int mt = 0; mt < 4; ++mt)
#pragma unroll
            for (int r = 0; r < 4; r += 2) {
                unsigned pk2 = f2bf2(fmaxf(acc2[mt][r] + bb, 0.f),
                                     fmaxf(acc2[mt][r + 1] + bb, 0.f));
                xb[(mt * 16 + q * 4 + r)     * H2_STRIDE + col] = (short)pk2;
                xb[(mt * 16 + q * 4 + r + 1) * H2_STRIDE + col] = (short)(pk2 >> 16);
            }
    }
    __syncthreads();   // b4: h2 ready; xa GEMM2 reads done

    // ---------- GEMM3: a1 = relu(h2 @ A1[:128] + s1) -> xa (stride 136) ----------
    {
        f32x4 acc3[4];
#pragma unroll
        for (int mt = 0; mt < 4; ++mt) {
            acc3[mt][0] = s1v; acc3[mt][1] = s1v; acc3[mt][2] = s1v; acc3[mt][3] = s1v;
        }
#pragma unroll
        for (int ks = 0; ks < 4; ++ks) {
            bf16x8 af[4];
#pragma unroll
            for (int mt = 0; mt < 4; ++mt)
                af[mt] = *(const bf16x8*)&xb[(mt * 16 + mr) * H2_STRIDE + ks * 32 + q * 8];
#pragma unroll
            for (int mt = 0; mt < 4; ++mt)
                acc3[mt] = __builtin_amdgcn_mfma_f32_16x16x32_bf16(af[mt], g3f[ks], acc3[mt], 0, 0, 0);
        }
        // preload ALL GEMM4 B-frags (hidden under GEMM3 epilogue + b5)
        const short* A2b = A2p + wv * 4 * 512 + lane * 8;
        bf16x8 g4f[4];
#pragma unroll
        for (int ks = 0; ks < 4; ++ks) g4f[ks] = *(const bf16x8*)&A2b[ks * 512];

        {
            const int col = wv * 16 + mr;
#pragma unroll
            for (int mt = 0; mt < 4; ++mt)
#pragma unroll
                for (int r = 0; r < 4; r += 2) {
                    unsigned pk2 = f2bf2(fmaxf(acc3[mt][r], 0.f),
                                         fmaxf(acc3[mt][r + 1], 0.f));
                    xa[(mt * 16 + q * 4 + r)     * A_STRIDE + col] = (short)pk2;
                    xa[(mt * 16 + q * 4 + r + 1) * A_STRIDE + col] = (short)(pk2 >> 16);
                }
        }
        __syncthreads();   // b5: a1 ready

        // ---------- GEMM4 + in-register logits ----------
        f32x4 acc4[4];
        {
            const float bv = ab2[wv * 16 + mr];
#pragma unroll
            for (int mt = 0; mt < 4; ++mt) {
                acc4[mt][0] = bv; acc4[mt][1] = bv; acc4[mt][2] = bv; acc4[mt][3] = bv;
            }
        }
#pragma unroll
        for (int ks = 0; ks < 4; ++ks) {
            bf16x8 af[4];
#pragma unroll
            for (int mt = 0; mt < 4; ++mt)
                af[mt] = *(const bf16x8*)&xa[(mt * 16 + mr) * A_STRIDE + ks * 32 + q * 8];
#pragma unroll
            for (int mt = 0; mt < 4; ++mt)
                acc4[mt] = __builtin_amdgcn_mfma_f32_16x16x32_bf16(af[mt], g4f[ks], acc4[mt], 0, 0, 0);
        }
        const float av = A3[wv * 16 + mr];
        float pl[4][4];
#pragma unroll
        for (int mt = 0; mt < 4; ++mt)
#pragma unroll
            for (int r = 0; r < 4; ++r)
                pl[mt][r] = fmaxf(acc4[mt][r], 0.f) * av;
#pragma unroll
        for (int off = 1; off < 16; off <<= 1)
#pragma unroll
            for (int mt = 0; mt < 4; ++mt)
#pragma unroll
                for (int r = 0; r < 4; ++r)
                    pl[mt][r] += __shfl_xor(pl[mt][r], off, 64);
        if (mr == 0) {
#pragma unroll
            for (int mt = 0; mt < 4; ++mt)
#pragma unroll
                for (int r = 0; r < 4; ++r)
                    partials[wv * KK + mt * 16 + q * 4 + r] = pl[mt][r];
        }
    }
    __syncthreads();   // b6 (final barrier)

    // ---------- distributed tail: every wave computes softmax redundantly ----------
    {
        float l = ab3[0];
#pragma unroll
        for (int w = 0; w < 8; ++w) l += partials[w * KK + lane];
        float m = l;
#pragma unroll
        for (int off = 32; off > 0; off >>= 1) m = fmaxf(m, __shfl_xor(m, off, 64));
        float e = expf(l - m);
        float s = e;
#pragma unroll
        for (int off = 32; off > 0; off >>= 1) s += __shfl_xor(s, off, 64);
        wts8[wv * 64 + lane] = e / s;          // wave-local write; same-wave read below
        // out[n][col]: wave wv covers cols wv*16..+15; lane (mr,q) sums k in [q*16,q*16+16)
        const int col = wv * 16 + mr;
        const float* wl = &wts8[wv * 64 + q * 16];
        const short* hp = &xb[(q * 16) * H2_STRIDE + col];
        float acc = 0.f;
#pragma unroll
        for (int j = 0; j < 16; ++j)
            acc = fmaf(wl[j], bf2f(hp[j * H2_STRIDE]), acc);
        acc += __shfl_xor(acc, 16, 64);
        acc += __shfl_xor(acc, 32, 64);
        if (q == 0) out[(size_t)n * DD + col] = acc;
    }
}

extern "C" void kernel_launch(void* const* d_in, const int* in_sizes, int n_in,
                              void* d_out, int out_size, void* d_ws, size_t ws_size,
                              hipStream_t stream)
{
    const int*   nodes     = (const int*)d_in[0];
    const int*   paths_rel = (const int*)d_in[1];
    const int*   paths_nbr = (const int*)d_in[2];
    const int*   attrs     = (const int*)d_in[3];
    const float* u2e  = (const float*)d_in[4];
    const float* r2e  = (const float*)d_in[5];
    const float* ua2e = (const float*)d_in[6];
    const float* W1   = (const float*)d_in[7];
    const float* b1   = (const float*)d_in[8];
    const float* W2   = (const float*)d_in[9];
    const float* b2   = (const float*)d_in[10];
    const float* A1   = (const float*)d_in[11];
    const float* ab1  = (const float*)d_in[12];
    const float* A2   = (const float*)d_in[13];
    const float* ab2  = (const float*)d_in[14];
    const float* A3   = (const float*)d_in[15];
    const float* ab3  = (const float*)d_in[16];
    float* out = (float*)d_out;

    // ws bytes:
    //       0  W1p   (262144)
    //  262144  W2p   ( 65536)
    //  327680  A1p   ( 32768)
    //  360448  A2p   ( 32768)
    //  393216  s1g   (2097152)
    // 2490368  u2b   (25600000)  -- bf16 u2e
    // 28090368 r2b   (8192)      -- bf16 r2e
    // 28098560 uab   (1280000)   -- bf16 ua2e
    // 29378560 = WS_NEED
    short* wsp = (short*)d_ws;
    short* W1p = wsp;
    short* W2p = wsp + 131072;
    short* A1p = wsp + 163840;
    short* A2p = wsp + 180224;
    float* s1g = (float*)((char*)d_ws + 393216);
    short* u2b = (short*)((char*)d_ws + 2490368);
    short* r2b = (short*)((char*)d_ws + 28090368);
    short* uab = (short*)((char*)d_ws + 28098560);

    const size_t WS_NEED = 29378560;
    const bool bft = (ws_size >= WS_NEED);

    // 96 pack + 512 s1 + 6565 conv = 7173 blocks, one launch
    prep_all<<<dim3(96 + 512 + 6565), dim3(256), 0, stream>>>(
        W1, W2, A1, A2, nodes, u2e, r2e, ua2e, ab1,
        W1p, W2p, A1p, A2p, s1g, u2b, r2b, uab);
    if (bft) {
        l2agg_mfma<true><<<dim3(NN), dim3(512), 0, stream>>>(
            paths_rel, paths_nbr, attrs, u2e, r2e, ua2e, u2b, r2b, uab,
            b1, b2, ab2, A3, ab3, W1p, W2p, A1p, A2p, s1g, out);
    } else {
        l2agg_mfma<false><<<dim3(NN), dim3(512), 0, stream>>>(
            paths_rel, paths_nbr, attrs, u2e, r2e, ua2e, u2b, r2b, uab,
            b1, b2, ab2, A3, ab3, W1p, W2p, A1p, A2p, s1g, out);
    }
}

// Round 6
// 269.380 us; speedup vs baseline: 1.0544x; 1.0544x over previous
//
#include <hip/hip_runtime.h>
#include <hip/hip_bf16.h>

#define NN 4096
#define KK 64
#define AA 8
#define DD 128

#define XH_STRIDE 264   // shorts: 256 + 8 pad (rows 16B-aligned)
#define A_STRIDE  136
#define H2_STRIDE 136
#define XREG_SZ   16896 // 64 * 264 shorts = 33792 B

typedef __bf16 bf16x8 __attribute__((ext_vector_type(8)));
typedef __bf16 bf16x2 __attribute__((ext_vector_type(2)));
typedef float  f32x4  __attribute__((ext_vector_type(4)));

__device__ __forceinline__ short f2bf(float f) {
    unsigned u = __builtin_bit_cast(unsigned, f);
    u += 0x7FFFu + ((u >> 16) & 1u);   // RNE
    return (short)(u >> 16);
}
__device__ __forceinline__ float bf2f(short s) {
    unsigned u = ((unsigned)(unsigned short)s) << 16;
    return __builtin_bit_cast(float, u);
}
__device__ __forceinline__ unsigned f2bf2(float a, float b) {
#if __has_builtin(__builtin_amdgcn_cvt_pk_bf16_f32)
    bf16x2 r = __builtin_amdgcn_cvt_pk_bf16_f32(a, b);
    return __builtin_bit_cast(unsigned, r);
#else
    return ((unsigned)(unsigned short)f2bf(a)) | (((unsigned)(unsigned short)f2bf(b)) << 16);
#endif
}
__device__ __forceinline__ void store_bf8(short* dst, float4 a, float4 b) {
    uint4 v;
    v.x = f2bf2(a.x, a.y); v.y = f2bf2(a.z, a.w);
    v.z = f2bf2(b.x, b.y); v.w = f2bf2(b.z, b.w);
    *(uint4*)dst = v;
}

// R14-kept: single-launch prep (pack + s1 + conv); block ranges:
// [0,96) weight pack (8 elems/thread) | [96,608) s1 | [608,7173) bf16 conv.
__global__ void prep_all(const float* __restrict__ W1, const float* __restrict__ W2,
                         const float* __restrict__ A1, const float* __restrict__ A2,
                         const int* __restrict__ nodes, const float* __restrict__ u2e,
                         const float* __restrict__ r2e, const float* __restrict__ ua2e,
                         const float* __restrict__ ab1,
                         short* __restrict__ W1p, short* __restrict__ W2p,
                         short* __restrict__ A1p, short* __restrict__ A2p,
                         float* __restrict__ s1g,
                         short* __restrict__ u2b, short* __restrict__ r2b,
                         short* __restrict__ uab)
{
    if (blockIdx.x < 96) {
        const int t    = blockIdx.x * 256 + threadIdx.x;   // [0, 24576)
        const int idx8 = t * 8;
        const float* src; short* dst; int Ncols, ksl, idx;
        if (idx8 < 131072)      { src = W1; dst = W1p; Ncols = 256; ksl = 4; idx = idx8; }
        else if (idx8 < 163840) { src = W2; dst = W2p; Ncols = 128; ksl = 3; idx = idx8 - 131072; }
        else if (idx8 < 180224) { src = A1; dst = A1p; Ncols = 128; ksl = 2; idx = idx8 - 163840; }
        else                    { src = A2; dst = A2p; Ncols = 128; ksl = 2; idx = idx8 - 180224; }
        const int lane  = (idx >> 3) & 63;
        const int fi    = idx >> 9;
        const int kstep = fi & ((1 << ksl) - 1);
        const int ntile = fi >> ksl;
        const int k0 = kstep * 32 + (lane >> 4) * 8;
        const int nn = ntile * 16 + (lane & 15);
        short v[8];
#pragma unroll
        for (int j = 0; j < 8; ++j)
            v[j] = f2bf(src[(size_t)(k0 + j) * Ncols + nn]);
        *(uint4*)&dst[idx] = *(const uint4*)v;
    } else if (blockIdx.x < 608) {
        // s1[n] = ab1 + u2e[nodes[n]] @ A1[128:256,:], 8 nodes/block
        __shared__ float rows[8][DD];
        const int b = blockIdx.x - 96;
        {
            const int r  = threadIdx.x >> 5;
            const int c4 = (threadIdx.x & 31) * 4;
            const int node = nodes[b * 8 + r];
            *(float4*)&rows[r][c4] = *(const float4*)&u2e[(size_t)node * DD + c4];
        }
        __syncthreads();
        const int h = threadIdx.x >> 7;
        const int c = threadIdx.x & 127;
        const float ab = ab1[c];
        float acc[4] = {ab, ab, ab, ab};
#pragma unroll 4
        for (int i = 0; i < DD; ++i) {
            const float av = A1[(size_t)(DD + i) * DD + c];
#pragma unroll
            for (int j = 0; j < 4; ++j)
                acc[j] = fmaf(rows[h * 4 + j][i], av, acc[j]);
        }
#pragma unroll
        for (int j = 0; j < 4; ++j)
            s1g[(size_t)(b * 8 + h * 4 + j) * DD + c] = acc[j];
    } else {
        // stream-convert embedding tables to bf16 (RNE, same bits as in-kernel cvt)
        const int t  = (blockIdx.x - 608) * 256 + threadIdx.x;
        const int e8 = t * 8;
        const float* src; short* dst; int off;
        if (e8 < 12800000)      { src = u2e;  dst = u2b; off = e8; }
        else if (e8 < 12804096) { src = r2e;  dst = r2b; off = e8 - 12800000; }
        else if (e8 < 13444096) { src = ua2e; dst = uab; off = e8 - 12804096; }
        else return;
        float4 a = *(const float4*)&src[off];
        float4 b = *(const float4*)&src[off + 4];
        store_bf8(&dst[off], a, b);
    }
}

// Register discipline (hard-won, R6/R8/R9/R14):
//  - launch_bounds MUST stay (512,4): (512,6) caps regs ~85/wave -> acc spill (R6).
//    3 blocks/CU is closed (needs 6 waves/EU budget). Occupancy door CLOSED.
//  - The gather phase cannot share a register window with ANYTHING:
//    R8 (manual interleave), R9 (compiler hoist), R14 (merged xA+xB staging)
//    all spilled (WRITE_SIZE 43/59/59 MB). The R12 phase structure below
//    (stage xA | b1 | GEMM1h1 | fence | stage xB | fence | b2 | GEMM1h2)
//    is the spill-free optimum. DO NOT merge staging phases.
//  - R10: do not trade L2 bytes for LDS cycles (2Mx4N remap was -3.5%).
//  - R12: bf16 tables -> gathers 36->18/thread, FETCH 102->44MB, 200->164us.
//  - R13: XOR bank-swizzle cut conflicts only 6% and spilled. The 1.78e7
//    SQ_LDS_BANK_CONFLICT is structural wave64-b128 serialization, TLP-hidden.
//    Conflict-chasing is a DEAD END here.
template<bool BFT>
__launch_bounds__(512, 4)
__global__ void l2agg_mfma(
    const int* __restrict__ paths_rel,
    const int* __restrict__ paths_nbr,
    const int* __restrict__ attrs,
    const float* __restrict__ u2e,
    const float* __restrict__ r2e,
    const float* __restrict__ ua2e,
    const short* __restrict__ u2b,
    const short* __restrict__ r2b,
    const short* __restrict__ uab,
    const float* __restrict__ b1,
    const float* __restrict__ b2,
    const float* __restrict__ ab2,
    const float* __restrict__ A3,
    const float* __restrict__ ab3,
    const short* __restrict__ W1p,
    const short* __restrict__ W2p,
    const short* __restrict__ A1p,
    const short* __restrict__ A2p,
    const float* __restrict__ s1g,
    float* __restrict__ out)
{
    // xa: xA (stride 264) -> h1 (stride 264) -> a1 (stride 136)
    // xb: xB (stride 264) -> h2 (stride 136, persists to final reduce)
    __shared__ short xa[XREG_SZ];            // 33792 B
    __shared__ short xb[XREG_SZ];            // 33792 B
    __shared__ int   idx_u[576];             // attrs(512)+nbr(64) (dead after xB) -> partials
    __shared__ float wts8[512];              // per-wave softmax weights (wave-local)
    float* partials = (float*)idx_u;         // 512 floats, born after b5

    const int n    = blockIdx.x;
    const int tid  = threadIdx.x;
    const int lane = tid & 63;
    const int wv   = tid >> 6;    // 0..7
    const int mr   = lane & 15;
    const int q    = lane >> 4;

    // ---------- async DMA prefetch: attrs + nbr indices -> LDS ----------
    {
        const int* ab = attrs + (size_t)n * KK * AA;
        __builtin_amdgcn_global_load_lds(
            (const __attribute__((address_space(1))) void*)(ab + wv * 64 + lane),
            (__attribute__((address_space(3))) void*)(idx_u + wv * 64), 4, 0, 0);
        if (wv == 0) {
            const int* nb = paths_nbr + (size_t)n * KK;
            __builtin_amdgcn_global_load_lds(
                (const __attribute__((address_space(1))) void*)(nb + lane),
                (__attribute__((address_space(3))) void*)(idx_u + 512), 4, 0, 0);
        }
    }

    // ---------- stage xA = [r1 | r2] for 64 paths ----------
#pragma unroll
    for (int pass = 0; pass < 2; ++pass) {
        const int p  = pass * 32 + (tid >> 4);
        const int t  = tid & 15;
        const int o  = t * 8;
        const int pk = n * KK + p;
        const int i0 = paths_rel[pk * 2 + 0];
        const int i1 = paths_rel[pk * 2 + 1];
        if constexpr (BFT) {
            uint4 v1 = *(const uint4*)&r2b[(size_t)i0 * DD + o];
            uint4 v2 = *(const uint4*)&r2b[(size_t)i1 * DD + o];
            *(uint4*)&xa[p * XH_STRIDE + o]       = v1;
            *(uint4*)&xa[p * XH_STRIDE + 128 + o] = v2;
        } else {
            float4 r1a = *(const float4*)&r2e[(size_t)i0 * DD + o];
            float4 r1b = *(const float4*)&r2e[(size_t)i0 * DD + o + 4];
            float4 r2a = *(const float4*)&r2e[(size_t)i1 * DD + o];
            float4 r2b_ = *(const float4*)&r2e[(size_t)i1 * DD + o + 4];
            store_bf8(&xa[p * XH_STRIDE + o], r1a, r1b);
            store_bf8(&xa[p * XH_STRIDE + 128 + o], r2a, r2b_);
        }
    }
    __syncthreads();   // b1: xa ready, idx DMA landed

    // ---------- GEMM1 half 1 (ks 0..7 on xa), 2-deep B prefetch ----------
    const short* W1b = W1p + wv * 2 * 16 * 512 + lane * 8;  // frag(nt,ks) = W1b[nt*8192 + ks*512]
    f32x4 acc1[4][2] = {};
    bf16x8 bfc[2], bfn[2];
#pragma unroll
    for (int nt = 0; nt < 2; ++nt) bfc[nt] = *(const bf16x8*)&W1b[nt * 8192];
#pragma unroll
    for (int ks = 0; ks < 8; ++ks) {
#pragma unroll
        for (int nt = 0; nt < 2; ++nt)
            bfn[nt] = *(const bf16x8*)&W1b[nt * 8192 + (ks + 1) * 512];
        bf16x8 af[4];
#pragma unroll
        for (int mt = 0; mt < 4; ++mt)
            af[mt] = *(const bf16x8*)&xa[(mt * 16 + mr) * XH_STRIDE + ks * 32 + q * 8];
#pragma unroll
        for (int nt = 0; nt < 2; ++nt)
#pragma unroll
            for (int mt = 0; mt < 4; ++mt)
                acc1[mt][nt] = __builtin_amdgcn_mfma_f32_16x16x32_bf16(af[mt], bfc[nt], acc1[mt][nt], 0, 0, 0);
#pragma unroll
        for (int nt = 0; nt < 2; ++nt) bfc[nt] = bfn[nt];   // ks=7 carries ks=8 frags across staging
    }

    // Fence: keep xB gathers OUT of GEMM1h1's register window (R9 spill lesson).
    __builtin_amdgcn_sched_barrier(0);

    // ---------- stage xB = [ne | ae] -> xb ----------
#pragma unroll
    for (int pass = 0; pass < 2; ++pass) {
        const int p  = pass * 32 + (tid >> 4);
        const int t  = tid & 15;
        const int og = t * 8;
        const int nb = idx_u[512 + p];
        if constexpr (BFT) {
            uint4 nev = *(const uint4*)&u2b[(size_t)nb * DD + og];
            float aes[8] = {0.f, 0.f, 0.f, 0.f, 0.f, 0.f, 0.f, 0.f};
#pragma unroll
            for (int a = 0; a < AA; ++a) {
                const int ai = idx_u[p * AA + a];
                uint4 w = *(const uint4*)&uab[(size_t)ai * DD + og];
                aes[0] += __builtin_bit_cast(float, w.x << 16);
                aes[1] += __builtin_bit_cast(float, w.x & 0xFFFF0000u);
                aes[2] += __builtin_bit_cast(float, w.y << 16);
                aes[3] += __builtin_bit_cast(float, w.y & 0xFFFF0000u);
                aes[4] += __builtin_bit_cast(float, w.z << 16);
                aes[5] += __builtin_bit_cast(float, w.z & 0xFFFF0000u);
                aes[6] += __builtin_bit_cast(float, w.w << 16);
                aes[7] += __builtin_bit_cast(float, w.w & 0xFFFF0000u);
            }
            *(uint4*)&xb[p * XH_STRIDE + og] = nev;
            uint4 pv;
            pv.x = f2bf2(aes[0], aes[1]); pv.y = f2bf2(aes[2], aes[3]);
            pv.z = f2bf2(aes[4], aes[5]); pv.w = f2bf2(aes[6], aes[7]);
            *(uint4*)&xb[p * XH_STRIDE + 128 + og] = pv;
        } else {
            float4 nea = *(const float4*)&u2e[(size_t)nb * DD + og];
            float4 neb = *(const float4*)&u2e[(size_t)nb * DD + og + 4];
            float4 aea = make_float4(0.f, 0.f, 0.f, 0.f);
            float4 aeb = make_float4(0.f, 0.f, 0.f, 0.f);
#pragma unroll
            for (int a = 0; a < AA; ++a) {
                const int ai = idx_u[p * AA + a];
                float4 va = *(const float4*)&ua2e[(size_t)ai * DD + og];
                float4 vb = *(const float4*)&ua2e[(size_t)ai * DD + og + 4];
                aea.x += va.x; aea.y += va.y; aea.z += va.z; aea.w += va.w;
                aeb.x += vb.x; aeb.y += vb.y; aeb.z += vb.z; aeb.w += vb.w;
            }
            store_bf8(&xb[p * XH_STRIDE + og], nea, neb);
            store_bf8(&xb[p * XH_STRIDE + 128 + og], aea, aeb);
        }
    }
    __builtin_amdgcn_sched_barrier(0);
    __syncthreads();   // b2: xb ready; xa GEMM1h1 reads done -> xa writable later

    // ---------- GEMM1 half 2 (ks 8..15 on xb) ----------
#pragma unroll
    for (int ks = 8; ks < 16; ++ks) {
        if (ks < 15) {
#pragma unroll
            for (int nt = 0; nt < 2; ++nt)
                bfn[nt] = *(const bf16x8*)&W1b[nt * 8192 + (ks + 1) * 512];
        }
        bf16x8 af[4];
#pragma unroll
        for (int mt = 0; mt < 4; ++mt)
            af[mt] = *(const bf16x8*)&xb[(mt * 16 + mr) * XH_STRIDE + (ks - 8) * 32 + q * 8];
#pragma unroll
        for (int nt = 0; nt < 2; ++nt)
#pragma unroll
            for (int mt = 0; mt < 4; ++mt)
                acc1[mt][nt] = __builtin_amdgcn_mfma_f32_16x16x32_bf16(af[mt], bfc[nt], acc1[mt][nt], 0, 0, 0);
        if (ks < 15) {
#pragma unroll
            for (int nt = 0; nt < 2; ++nt) bfc[nt] = bfn[nt];
        }
    }

    // preload GEMM2 ks=0 B-frag; wave -> cols wv*16..wv*16+15 (mt4 x nt1: min regs)
    const short* W2b = W2p + wv * 8 * 512 + lane * 8;       // frag(ks) = W2b[ks*512]
    bf16x8 g2c = *(const bf16x8*)&W2b[0], g2n;

    // ---------- h1 = relu(acc1 + b1) -> xa (writable since b2) ----------
#pragma unroll
    for (int nt = 0; nt < 2; ++nt) {
        const int col = (wv * 2 + nt) * 16 + mr;
        const float bb = b1[col];
#pragma unroll
        for (int mt = 0; mt < 4; ++mt)
#pragma unroll
            for (int r = 0; r < 4; r += 2) {
                unsigned pk2 = f2bf2(fmaxf(acc1[mt][nt][r] + bb, 0.f),
                                     fmaxf(acc1[mt][nt][r + 1] + bb, 0.f));
                xa[(mt * 16 + q * 4 + r)     * XH_STRIDE + col] = (short)pk2;
                xa[(mt * 16 + q * 4 + r + 1) * XH_STRIDE + col] = (short)(pk2 >> 16);
            }
    }
    __syncthreads();   // b3: h1 ready; xb GEMM1h2 reads done

    // ---------- GEMM2: h2 = relu(h1 @ W2 + b2), 2-deep B prefetch ----------
    f32x4 acc2[4] = {};
#pragma unroll
    for (int ks = 0; ks < 8; ++ks) {
        if (ks < 7) g2n = *(const bf16x8*)&W2b[(ks + 1) * 512];
        bf16x8 af[4];
#pragma unroll
        for (int mt = 0; mt < 4; ++mt)
            af[mt] = *(const bf16x8*)&xa[(mt * 16 + mr) * XH_STRIDE + ks * 32 + q * 8];
#pragma unroll
        for (int mt = 0; mt < 4; ++mt)
            acc2[mt] = __builtin_amdgcn_mfma_f32_16x16x32_bf16(af[mt], g2c, acc2[mt], 0, 0, 0);
        if (ks < 7) g2c = g2n;
    }

    // preload ALL GEMM3 B-frags + s1 (hidden under GEMM2 epilogue + b4)
    const short* A1b = A1p + wv * 4 * 512 + lane * 8;
    bf16x8 g3f[4];
#pragma unroll
    for (int ks = 0; ks < 4; ++ks) g3f[ks] = *(const bf16x8*)&A1b[ks * 512];
    const float s1v = s1g[(size_t)n * DD + wv * 16 + mr];

    // GEMM2 epilogue -> h2 into xb (stride 136; xb dead since b3)
    {
        const int col = wv * 16 + mr;
        const float bb = b2[col];
#pragma unroll
        for (int mt = 0; mt < 4; ++mt)
#pragma unroll
            for (int r = 0; r < 4; r += 2) {
                unsigned pk2 = f2bf2(fmaxf(acc2[mt][r] + bb, 0.f),
                                     fmaxf(acc2[mt][r + 1] + bb, 0.f));
                xb[(mt * 16 + q * 4 + r)     * H2_STRIDE + col] = (short)pk2;
                xb[(mt * 16 + q * 4 + r + 1) * H2_STRIDE + col] = (short)(pk2 >> 16);
            }
    }
    __syncthreads();   // b4: h2 ready; xa GEMM2 reads done

    // ---------- GEMM3: a1 = relu(h2 @ A1[:128] + s1) -> xa (stride 136) ----------
    {
        f32x4 acc3[4];
#pragma unroll
        for (int mt = 0; mt < 4; ++mt) {
            acc3[mt][0] = s1v; acc3[mt][1] = s1v; acc3[mt][2] = s1v; acc3[mt][3] = s1v;
        }
#pragma unroll
        for (int ks = 0; ks < 4; ++ks) {
            bf16x8 af[4];
#pragma unroll
            for (int mt = 0; mt < 4; ++mt)
                af[mt] = *(const bf16x8*)&xb[(mt * 16 + mr) * H2_STRIDE + ks * 32 + q * 8];
#pragma unroll
            for (int mt = 0; mt < 4; ++mt)
                acc3[mt] = __builtin_amdgcn_mfma_f32_16x16x32_bf16(af[mt], g3f[ks], acc3[mt], 0, 0, 0);
        }
        // preload ALL GEMM4 B-frags (hidden under GEMM3 epilogue + b5)
        const short* A2b = A2p + wv * 4 * 512 + lane * 8;
        bf16x8 g4f[4];
#pragma unroll
        for (int ks = 0; ks < 4; ++ks) g4f[ks] = *(const bf16x8*)&A2b[ks * 512];

        {
            const int col = wv * 16 + mr;
#pragma unroll
            for (int mt = 0; mt < 4; ++mt)
#pragma unroll
                for (int r = 0; r < 4; r += 2) {
                    unsigned pk2 = f2bf2(fmaxf(acc3[mt][r], 0.f),
                                         fmaxf(acc3[mt][r + 1], 0.f));
                    xa[(mt * 16 + q * 4 + r)     * A_STRIDE + col] = (short)pk2;
                    xa[(mt * 16 + q * 4 + r + 1) * A_STRIDE + col] = (short)(pk2 >> 16);
                }
        }
        __syncthreads();   // b5: a1 ready

        // ---------- GEMM4 + in-register logits ----------
        f32x4 acc4[4];
        {
            const float bv = ab2[wv * 16 + mr];
#pragma unroll
            for (int mt = 0; mt < 4; ++mt) {
                acc4[mt][0] = bv; acc4[mt][1] = bv; acc4[mt][2] = bv; acc4[mt][3] = bv;
            }
        }
#pragma unroll
        for (int ks = 0; ks < 4; ++ks) {
            bf16x8 af[4];
#pragma unroll
            for (int mt = 0; mt < 4; ++mt)
                af[mt] = *(const bf16x8*)&xa[(mt * 16 + mr) * A_STRIDE + ks * 32 + q * 8];
#pragma unroll
            for (int mt = 0; mt < 4; ++mt)
                acc4[mt] = __builtin_amdgcn_mfma_f32_16x16x32_bf16(af[mt], g4f[ks], acc4[mt], 0, 0, 0);
        }
        const float av = A3[wv * 16 + mr];
        float pl[4][4];
#pragma unroll
        for (int mt = 0; mt < 4; ++mt)
#pragma unroll
            for (int r = 0; r < 4; ++r)
                pl[mt][r] = fmaxf(acc4[mt][r], 0.f) * av;
#pragma unroll
        for (int off = 1; off < 16; off <<= 1)
#pragma unroll
            for (int mt = 0; mt < 4; ++mt)
#pragma unroll
                for (int r = 0; r < 4; ++r)
                    pl[mt][r] += __shfl_xor(pl[mt][r], off, 64);
        if (mr == 0) {
#pragma unroll
            for (int mt = 0; mt < 4; ++mt)
#pragma unroll
                for (int r = 0; r < 4; ++r)
                    partials[wv * KK + mt * 16 + q * 4 + r] = pl[mt][r];
        }
    }
    __syncthreads();   // b6 (final barrier)

    // ---------- distributed tail: every wave computes softmax redundantly ----------
    {
        float l = ab3[0];
#pragma unroll
        for (int w = 0; w < 8; ++w) l += partials[w * KK + lane];
        float m = l;
#pragma unroll
        for (int off = 32; off > 0; off >>= 1) m = fmaxf(m, __shfl_xor(m, off, 64));
        float e = expf(l - m);
        float s = e;
#pragma unroll
        for (int off = 32; off > 0; off >>= 1) s += __shfl_xor(s, off, 64);
        wts8[wv * 64 + lane] = e / s;          // wave-local write; same-wave read below
        // out[n][col]: wave wv covers cols wv*16..+15; lane (mr,q) sums k in [q*16,q*16+16)
        const int col = wv * 16 + mr;
        const float* wl = &wts8[wv * 64 + q * 16];
        const short* hp = &xb[(q * 16) * H2_STRIDE + col];
        float acc = 0.f;
#pragma unroll
        for (int j = 0; j < 16; ++j)
            acc = fmaf(wl[j], bf2f(hp[j * H2_STRIDE]), acc);
        acc += __shfl_xor(acc, 16, 64);
        acc += __shfl_xor(acc, 32, 64);
        if (q == 0) out[(size_t)n * DD + col] = acc;
    }
}

extern "C" void kernel_launch(void* const* d_in, const int* in_sizes, int n_in,
                              void* d_out, int out_size, void* d_ws, size_t ws_size,
                              hipStream_t stream)
{
    const int*   nodes     = (const int*)d_in[0];
    const int*   paths_rel = (const int*)d_in[1];
    const int*   paths_nbr = (const int*)d_in[2];
    const int*   attrs     = (const int*)d_in[3];
    const float* u2e  = (const float*)d_in[4];
    const float* r2e  = (const float*)d_in[5];
    const float* ua2e = (const float*)d_in[6];
    const float* W1   = (const float*)d_in[7];
    const float* b1   = (const float*)d_in[8];
    const float* W2   = (const float*)d_in[9];
    const float* b2   = (const float*)d_in[10];
    const float* A1   = (const float*)d_in[11];
    const float* ab1  = (const float*)d_in[12];
    const float* A2   = (const float*)d_in[13];
    const float* ab2  = (const float*)d_in[14];
    const float* A3   = (const float*)d_in[15];
    const float* ab3  = (const float*)d_in[16];
    float* out = (float*)d_out;

    // ws bytes:
    //       0  W1p   (262144)
    //  262144  W2p   ( 65536)
    //  327680  A1p   ( 32768)
    //  360448  A2p   ( 32768)
    //  393216  s1g   (2097152)
    // 2490368  u2b   (25600000)  -- bf16 u2e
    // 28090368 r2b   (8192)      -- bf16 r2e
    // 28098560 uab   (1280000)   -- bf16 ua2e
    // 29378560 = WS_NEED
    short* wsp = (short*)d_ws;
    short* W1p = wsp;
    short* W2p = wsp + 131072;
    short* A1p = wsp + 163840;
    short* A2p = wsp + 180224;
    float* s1g = (float*)((char*)d_ws + 393216);
    short* u2b = (short*)((char*)d_ws + 2490368);
    short* r2b = (short*)((char*)d_ws + 28090368);
    short* uab = (short*)((char*)d_ws + 28098560);

    const size_t WS_NEED = 29378560;
    const bool bft = (ws_size >= WS_NEED);

    // 96 pack + 512 s1 + 6565 conv = 7173 blocks, one launch
    prep_all<<<dim3(96 + 512 + 6565), dim3(256), 0, stream>>>(
        W1, W2, A1, A2, nodes, u2e, r2e, ua2e, ab1,
        W1p, W2p, A1p, A2p, s1g, u2b, r2b, uab);
    if (bft) {
        l2agg_mfma<true><<<dim3(NN), dim3(512), 0, stream>>>(
            paths_rel, paths_nbr, attrs, u2e, r2e, ua2e, u2b, r2b, uab,
            b1, b2, ab2, A3, ab3, W1p, W2p, A1p, A2p, s1g, out);
    } else {
        l2agg_mfma<false><<<dim3(NN), dim3(512), 0, stream>>>(
            paths_rel, paths_nbr, attrs, u2e, r2e, ua2e, u2b, r2b, uab,
            b1, b2, ab2, A3, ab3, W1p, W2p, A1p, A2p, s1g, out);
    }
}